// Round 7
// baseline (154.495 us; speedup 1.0000x reference)
//
#include <hip/hip_runtime.h>

#define NTOK 8192
#define DDIM 1024
#define NEXP 16
#define NPAIR 136   // E*(E+1)/2 pairs with e<=f
#define NREP 8      // s_glob replicas (atomic spread)
#define XROW 1032   // LDS x-tile row stride (pad 8 floats: 2-way alias only)

typedef float vfloat4 __attribute__((ext_vector_type(4)));  // native vec for nontemporal builtin

// ws layout (floats):
//   gwT4  [4096 float4]      = 16384 f
//   s_glob[NREP*1024]        =  8192 f
//   G_part[16*136]           =  2176 f
//   route [NTOK float4]      = 32768 f
#define WS_GWT 0
#define WS_SG  16384
#define WS_GP  (16384 + NREP * DDIM)
#define WS_RT  (16384 + NREP * DDIM + 16 * NPAIR)

// ---------------------------------------------------------------------------
// Prep: transpose gate_w [16][1024] -> gwT4[d4][e] (float4 over d, expert-
// contiguous -> routing gate reads are 256B-contiguous). Zeroes s_glob.
// ---------------------------------------------------------------------------
__global__ __launch_bounds__(256) void moe_prep(
    const float* __restrict__ gate_w,
    float* __restrict__ ws)
{
    const int gid = blockIdx.x * 256 + threadIdx.x;   // 0..4095
    const int e = gid & 15;
    const int d4 = gid >> 4;                          // 0..255
    const float4* gw4 = (const float4*)gate_w;
    float4* gwT4 = (float4*)(ws + WS_GWT);
    gwT4[d4 * 16 + e] = gw4[e * 256 + d4];
    float* s_glob = ws + WS_SG;
    s_glob[gid] = 0.f;
    s_glob[gid + 4096] = 0.f;
}

// ---------------------------------------------------------------------------
// Routing: 1024 blocks x 256 thr, 8 tokens/block. Phase A stages the x-tile
// to LDS coalesced and computes x^2 column partials (thread owns d-cols
// 4t..4t+3, no reduction needed). Phase B: lane=(g tok, h half, e expert)
// does a 512-d half-dot from LDS x (broadcast) and gwT (coalesced stream);
// shfl_xor(16) merges. Phase C: stable top2; 16B route record per token.
// ---------------------------------------------------------------------------
__global__ __launch_bounds__(256, 4) void moe_route(
    const float* __restrict__ x,
    const float* __restrict__ gate_b,
    float* __restrict__ ws)
{
    __shared__ float xt[8][XROW];

    const int t = threadIdx.x;
    const int b = blockIdx.x;
    const float4* gwT4 = (const float4*)(ws + WS_GWT);
    float* s_glob = ws + WS_SG;
    float4* route = (float4*)(ws + WS_RT);

    // ---- A: stage 8 token rows, accumulate x^2 for owned d-columns ----
    float4 ss = make_float4(0.f, 0.f, 0.f, 0.f);
    {
        const float4* x4 = (const float4*)x + (size_t)b * 2048;
        #pragma unroll
        for (int i = 0; i < 8; ++i) {
            float4 v = x4[i * 256 + t];
            *(float4*)&xt[i][4 * t] = v;
            ss.x = fmaf(v.x, v.x, ss.x);
            ss.y = fmaf(v.y, v.y, ss.y);
            ss.z = fmaf(v.z, v.z, ss.z);
            ss.w = fmaf(v.w, v.w, ss.w);
        }
    }
    __syncthreads();

    const int lane = t & 63;
    const int wave = t >> 6;
    const int e = lane & 15;
    const int h = (lane >> 4) & 1;
    const int g = lane >> 5;

    // ---- B: routing half-dot ----
    const int tokL = wave * 2 + g;
    const float* xrow = &xt[tokL][h * 512];
    const float4* gt = gwT4 + h * 128 * 16;
    float4 a4 = make_float4(0.f, 0.f, 0.f, 0.f);
    #pragma unroll 8
    for (int i = 0; i < 128; ++i) {
        float4 xv = *(const float4*)(xrow + 4 * i);  // LDS broadcast
        float4 gv = gt[i * 16 + e];                  // 256B contiguous stream
        a4.x = fmaf(xv.x, gv.x, a4.x);
        a4.y = fmaf(xv.y, gv.y, a4.y);
        a4.z = fmaf(xv.z, gv.z, a4.z);
        a4.w = fmaf(xv.w, gv.w, a4.w);
    }
    float acc = (a4.x + a4.y) + (a4.z + a4.w);
    acc += __shfl_xor(acc, 16, 64);                  // merge d-halves
    acc += gate_b[e];

    // ---- C: stable top2 scan (matches lax.top_k tie-break) ----
    float v0 = -3.0e38f, v1 = -3.0e38f;
    int i0 = 0, i1 = 0;
    const int base = lane & 32;
    #pragma unroll
    for (int j = 0; j < NEXP; ++j) {
        float lv = __shfl(acc, base + j, 64);
        if (lv > v0)      { v1 = v0; i1 = i0; v0 = lv; i0 = j; }
        else if (lv > v1) { v1 = lv; i1 = j; }
    }
    float ex = __expf(v1 - v0);                      // softmax denom cancels
    float w0 = 1.f / (1.f + ex);
    float w1 = ex * w0;

    if ((lane & 31) == 0)   // one writer per token (lane 0 -> g0, lane 32 -> g1)
        route[b * 8 + tokL] =
            make_float4(w0, w1, __int_as_float(i0), __int_as_float(i1));

    // ---- x^2 partials: thread owns its 4 d-columns exclusively ----
    {
        float* rep = s_glob + (size_t)(b & (NREP - 1)) * DDIM;
        atomicAdd(&rep[4 * t + 0], ss.x);
        atomicAdd(&rep[4 * t + 1], ss.y);
        atomicAdd(&rep[4 * t + 2], ss.z);
        atomicAdd(&rep[4 * t + 3], ss.w);
    }
}

// ---------------------------------------------------------------------------
// Combine: pure streaming, no LDS, no barriers. 2048 blocks x 256 thr;
// wave = one token. Read 16B route rec (broadcast), x row + 2 re rows
// (coalesced float4), write out with non-temporal stores.
// ---------------------------------------------------------------------------
__global__ __launch_bounds__(256, 8) void moe_combine(
    const float* __restrict__ x,
    const float* __restrict__ sh,
    const float* __restrict__ re,
    const float* __restrict__ ws,
    float* __restrict__ out)
{
    const int t = threadIdx.x;
    const int lane = t & 63;
    const int n = blockIdx.x * 4 + (t >> 6);
    const float4* route = (const float4*)(ws + WS_RT);

    float4 rec = route[n];
    const float a0 = rec.x, a1 = rec.y;
    const int e0 = __float_as_int(rec.z);
    const int e1 = __float_as_int(rec.w);

    const float4* s0 = (const float4*)sh;
    const float4* s1 = (const float4*)(sh + DDIM);
    const float4* xr = (const float4*)(x + (size_t)n * DDIM);
    const float4* r0 = (const float4*)(re + (size_t)e0 * DDIM);
    const float4* r1 = (const float4*)(re + (size_t)e1 * DDIM);
    vfloat4* o = (vfloat4*)(out + (size_t)n * DDIM);

    #pragma unroll
    for (int j = 0; j < 4; ++j) {
        const int idx = lane + 64 * j;
        float4 xv = xr[idx];
        float4 p  = s0[idx];
        float4 q  = s1[idx];
        float4 b0 = r0[idx];
        float4 b1 = r1[idx];
        vfloat4 r;
        r.x = xv.x * ((p.x + q.x) + a0 * b0.x + a1 * b1.x);
        r.y = xv.y * ((p.y + q.y) + a0 * b0.y + a1 * b1.y);
        r.z = xv.z * ((p.z + q.z) + a0 * b0.z + a1 * b1.z);
        r.w = xv.w * ((p.w + q.w) + a0 * b0.w + a1 * b1.w);
        __builtin_nontemporal_store(r, &o[idx]);
    }
}

// ---------------------------------------------------------------------------
// Partial Gram: block b covers d-chunk [64b, 64b+64); writes G_part[b][136].
// ---------------------------------------------------------------------------
__global__ __launch_bounds__(320) void moe_div_partial(
    const float* __restrict__ re,
    float* __restrict__ ws)
{
    __shared__ float reT[64][17];
    __shared__ float s4[4][64];
    __shared__ float s_loc[64];

    const int t = threadIdx.x;
    const int b = blockIdx.x;
    const int d0 = b * 64;
    const float* s_glob = ws + WS_SG;
    float* G_part = ws + WS_GP;

    if (t < 256) {
        int c = t & 63, r = t >> 6;
        s4[r][c] = s_glob[r * DDIM + d0 + c] + s_glob[(r + 4) * DDIM + d0 + c];
        int e = t >> 4, d4 = t & 15;
        float4 v = ((const float4*)(re + (size_t)e * DDIM + d0))[d4];
        reT[d4 * 4 + 0][e] = v.x;
        reT[d4 * 4 + 1][e] = v.y;
        reT[d4 * 4 + 2][e] = v.z;
        reT[d4 * 4 + 3][e] = v.w;
    }
    __syncthreads();
    if (t < 64) s_loc[t] = (s4[0][t] + s4[1][t]) + (s4[2][t] + s4[3][t]);
    __syncthreads();

    const int p = t >> 1;
    const int half = t & 1;
    float a = 0.f;
    if (p < NPAIR) {
        int pe = 0, rem = p;
        while (rem >= NEXP - pe) { rem -= NEXP - pe; ++pe; }
        int pf = pe + rem;
        #pragma unroll
        for (int i = 0; i < 32; ++i) {
            int dd = half * 32 + i;
            a += s_loc[dd] * reT[dd][pe] * reT[dd][pf];
        }
    }
    a += __shfl_down(a, 1, 64);
    if (p < NPAIR && half == 0) G_part[b * NPAIR + p] = a;
}

// ---------------------------------------------------------------------------
// Finalize: sum 16 partial Grams, norms, clipped cosine mean * lambda.
// ---------------------------------------------------------------------------
__global__ __launch_bounds__(192) void moe_div_final(
    const float* __restrict__ ws,
    float* __restrict__ div_out)
{
    __shared__ float G[NPAIR];
    __shared__ float nr[NEXP];
    __shared__ float lsum;
    const float* G_part = ws + WS_GP;
    const int t = threadIdx.x;

    if (t == 0) lsum = 0.f;
    if (t < NPAIR) {
        float g = 0.f;
        #pragma unroll
        for (int b = 0; b < 16; ++b) g += G_part[b * NPAIR + t];
        G[t] = g;
    }
    __syncthreads();
    if (t < NEXP) {
        int idx = t * NEXP - (t * (t - 1)) / 2;   // diagonal (t,t)
        nr[t] = fmaxf(sqrtf(G[idx]), 1e-8f);
    }
    __syncthreads();
    if (t < NPAIR) {
        int pe = 0, rem = t;
        while (rem >= NEXP - pe) { rem -= NEXP - pe; ++pe; }
        int pf = pe + rem;
        if (pe != pf) {
            float sim = G[t] / (nr[pe] * nr[pf]);
            sim = fminf(1.f, fmaxf(-1.f, sim));
            atomicAdd(&lsum, 2.f * sim);
        }
    }
    __syncthreads();
    if (t == 0) *div_out = lsum / (float)(NEXP * (NEXP - 1)) * 0.1f;
}

extern "C" void kernel_launch(void* const* d_in, const int* in_sizes, int n_in,
                              void* d_out, int out_size, void* d_ws, size_t ws_size,
                              hipStream_t stream) {
    const float* x  = (const float*)d_in[0];
    const float* gw = (const float*)d_in[1];
    const float* gb = (const float*)d_in[2];
    const float* sh = (const float*)d_in[3];
    const float* re = (const float*)d_in[4];
    float* out = (float*)d_out;
    float* ws = (float*)d_ws;   // needs ~240 KB

    moe_prep<<<16, 256, 0, stream>>>(gw, ws);
    moe_route<<<1024, 256, 0, stream>>>(x, gb, ws);
    moe_combine<<<2048, 256, 0, stream>>>(x, sh, re, ws, out);
    moe_div_partial<<<16, 320, 0, stream>>>(re, ws);
    moe_div_final<<<1, 192, 0, stream>>>(ws, out + (size_t)NTOK * DDIM);
}

// Round 8
// 132.838 us; speedup vs baseline: 1.1630x; 1.1630x over previous
//
#include <hip/hip_runtime.h>

#define NTOK 8192
#define DDIM 1024
#define NEXP 16
#define NPAIR 136   // E*(E+1)/2 pairs with e<=f
#define NREP 16     // s_glob replicas (atomic spread; 2048 blocks / 16 = 128 adds/word)
#define NCHUNK 8
#define CK 128      // K per gate chunk

// ws layout (floats): gwT4 [4096 float4] = 16384 f | s_glob [NREP*1024] | G_part [16*136]
#define WS_GWT 0
#define WS_SG  16384
#define WS_GP  (16384 + NREP * DDIM)

// ---------------------------------------------------------------------------
// Prep: transpose gate_w [16][1024] -> gwT4[d4][e] (float4 over d, expert-
// contiguous). Zeroes the 16 s_glob replicas. One dispatch, ~2 us.
// ---------------------------------------------------------------------------
__global__ __launch_bounds__(256) void moe_prep(
    const float* __restrict__ gate_w,
    float* __restrict__ ws)
{
    const int gid = blockIdx.x * 256 + threadIdx.x;   // 0..4095
    const int e = gid & 15;
    const int d4 = gid >> 4;                          // 0..255
    const float4* gw4 = (const float4*)gate_w;
    float4* gwT4 = (float4*)(ws + WS_GWT);
    gwT4[d4 * 16 + e] = gw4[e * 256 + d4];
    float* s_glob = ws + WS_SG;
    s_glob[gid]         = 0.f;
    s_glob[gid + 4096]  = 0.f;
    s_glob[gid + 8192]  = 0.f;
    s_glob[gid + 12288] = 0.f;
}

// ---------------------------------------------------------------------------
// Fused: 2048 blocks x 256 thr, 4 tokens/block, 1 token/wave.
// A: x-tile (4x1024, 16 KB) -> LDS once; thread t owns cols 4t..4t+3 ->
//    x^2 partials need no reduction.
// B: K-chunked router GEMM: per chunk, the BLOCK cooperatively stages an
//    8 KB gate chunk (2 coalesced float4/thread) -> compute reads it from
//    LDS (lane=(e,q): e=expert, q=K-quarter; 2-way bank alias = free).
//    Gate L2 traffic: 64 KB/block (vs 64 KB/WAVE in R4). Two shfl_xor
//    merge the quarters into full logits in every lane.
// C: stable top2 scan (matches lax.top_k); weights via sigmoid (softmax
//    denominator cancels in top-2 renormalization).
// D: combine from LDS x + L2-hot re rows, coalesced float4 out.
// ---------------------------------------------------------------------------
__global__ __launch_bounds__(256, 6) void moe_fused(
    const float* __restrict__ x,
    const float* __restrict__ gate_b,
    const float* __restrict__ sh,
    const float* __restrict__ re,
    float* __restrict__ out,
    float* __restrict__ ws)
{
    __shared__ float xt[4][DDIM];        // 16 KB
    __shared__ float4 gl[(CK / 4) * NEXP];  // 512 float4 = 8 KB

    const int t = threadIdx.x;
    const int b = blockIdx.x;
    const float4* gwT4 = (const float4*)(ws + WS_GWT);

    // ---- A: stage 4 token rows, x^2 partials for owned columns ----
    float4 ss = make_float4(0.f, 0.f, 0.f, 0.f);
    {
        const float4* x4 = (const float4*)x + (size_t)b * 1024;
        #pragma unroll
        for (int i = 0; i < 4; ++i) {
            float4 v = x4[i * 256 + t];
            *(float4*)&xt[i][4 * t] = v;
            ss.x = fmaf(v.x, v.x, ss.x);
            ss.y = fmaf(v.y, v.y, ss.y);
            ss.z = fmaf(v.z, v.z, ss.z);
            ss.w = fmaf(v.w, v.w, ss.w);
        }
    }
    __syncthreads();

    const int lane = t & 63;
    const int w = t >> 6;        // token within block
    const int e = lane & 15;     // expert
    const int q = lane >> 4;     // K-quarter of chunk

    // ---- B: chunked router GEMM ----
    float4 acc = make_float4(0.f, 0.f, 0.f, 0.f);
    for (int c = 0; c < NCHUNK; ++c) {
        gl[t]       = gwT4[c * 512 + t];
        gl[t + 256] = gwT4[c * 512 + 256 + t];
        __syncthreads();
        const float* xrow = &xt[w][c * CK];
        #pragma unroll
        for (int i = 0; i < 8; ++i) {
            const int k4 = q * 8 + i;
            float4 xv = *(const float4*)(xrow + 4 * k4);  // 4 addrs, 16-way bcast
            float4 gv = gl[k4 * 16 + e];                  // 2-way alias, free
            acc.x = fmaf(xv.x, gv.x, acc.x);
            acc.y = fmaf(xv.y, gv.y, acc.y);
            acc.z = fmaf(xv.z, gv.z, acc.z);
            acc.w = fmaf(xv.w, gv.w, acc.w);
        }
        __syncthreads();
    }
    float s = (acc.x + acc.y) + (acc.z + acc.w);
    s += __shfl_xor(s, 16, 64);
    s += __shfl_xor(s, 32, 64);          // all quarters merged
    s += gate_b[e];

    // ---- C: stable top2 over the 16 expert lanes (q-uniform) ----
    float v0 = -3.0e38f, v1 = -3.0e38f;
    int i0 = 0, i1 = 0;
    const int base = lane & 48;
    #pragma unroll
    for (int j = 0; j < NEXP; ++j) {
        float lv = __shfl(s, base + j, 64);
        if (lv > v0)      { v1 = v0; i1 = i0; v0 = lv; i0 = j; }
        else if (lv > v1) { v1 = lv; i1 = j; }
    }
    float ex = __expf(v1 - v0);          // softmax denom cancels
    float w0 = 1.f / (1.f + ex);
    float w1 = ex * w0;
    // every lane of the wave now holds identical (w0,w1,i0,i1) -> no bcast

    // ---- D: combine token w ----
    const float4* s0 = (const float4*)sh;
    const float4* s1 = (const float4*)(sh + DDIM);
    const float4* r0 = (const float4*)(re + (size_t)i0 * DDIM);
    const float4* r1 = (const float4*)(re + (size_t)i1 * DDIM);
    float4* o = (float4*)(out + ((size_t)b * 4 + w) * DDIM);
    #pragma unroll
    for (int j = 0; j < 4; ++j) {
        const int idx = lane + 64 * j;
        float4 xv = *(const float4*)&xt[w][4 * idx];
        float4 p  = s0[idx];
        float4 qq = s1[idx];
        float4 b0 = r0[idx];
        float4 b1 = r1[idx];
        float4 r;
        r.x = xv.x * ((p.x + qq.x) + w0 * b0.x + w1 * b1.x);
        r.y = xv.y * ((p.y + qq.y) + w0 * b0.y + w1 * b1.y);
        r.z = xv.z * ((p.z + qq.z) + w0 * b0.z + w1 * b1.z);
        r.w = xv.w * ((p.w + qq.w) + w0 * b0.w + w1 * b1.w);
        o[idx] = r;
    }

    // ---- x^2 partials: exclusive columns -> 4 global atomics/thread ----
    {
        float* rep = ws + WS_SG + (size_t)(b & (NREP - 1)) * DDIM;
        atomicAdd(&rep[4 * t + 0], ss.x);
        atomicAdd(&rep[4 * t + 1], ss.y);
        atomicAdd(&rep[4 * t + 2], ss.z);
        atomicAdd(&rep[4 * t + 3], ss.w);
    }
}

// ---------------------------------------------------------------------------
// Partial Gram: block b covers d-chunk [64b, 64b+64); writes G_part[b][136].
// ---------------------------------------------------------------------------
__global__ __launch_bounds__(320) void moe_div_partial(
    const float* __restrict__ re,
    float* __restrict__ ws)
{
    __shared__ float reT[64][17];
    __shared__ float s4[4][64];
    __shared__ float s_loc[64];

    const int t = threadIdx.x;
    const int b = blockIdx.x;
    const int d0 = b * 64;
    const float* s_glob = ws + WS_SG;
    float* G_part = ws + WS_GP;

    if (t < 256) {
        int c = t & 63, r = t >> 6;
        s4[r][c] = (s_glob[r * DDIM + d0 + c] + s_glob[(r + 4) * DDIM + d0 + c])
                 + (s_glob[(r + 8) * DDIM + d0 + c] + s_glob[(r + 12) * DDIM + d0 + c]);
        int e = t >> 4, d4 = t & 15;
        float4 v = ((const float4*)(re + (size_t)e * DDIM + d0))[d4];
        reT[d4 * 4 + 0][e] = v.x;
        reT[d4 * 4 + 1][e] = v.y;
        reT[d4 * 4 + 2][e] = v.z;
        reT[d4 * 4 + 3][e] = v.w;
    }
    __syncthreads();
    if (t < 64) s_loc[t] = (s4[0][t] + s4[1][t]) + (s4[2][t] + s4[3][t]);
    __syncthreads();

    const int p = t >> 1;
    const int half = t & 1;
    float a = 0.f;
    if (p < NPAIR) {
        int pe = 0, rem = p;
        while (rem >= NEXP - pe) { rem -= NEXP - pe; ++pe; }
        int pf = pe + rem;
        #pragma unroll
        for (int i = 0; i < 32; ++i) {
            int dd = half * 32 + i;
            a += s_loc[dd] * reT[dd][pe] * reT[dd][pf];
        }
    }
    a += __shfl_down(a, 1, 64);
    if (p < NPAIR && half == 0) G_part[b * NPAIR + p] = a;
}

// ---------------------------------------------------------------------------
// Finalize: sum 16 partial Grams, norms, clipped cosine mean * lambda.
// ---------------------------------------------------------------------------
__global__ __launch_bounds__(192) void moe_div_final(
    const float* __restrict__ ws,
    float* __restrict__ div_out)
{
    __shared__ float G[NPAIR];
    __shared__ float nr[NEXP];
    __shared__ float lsum;
    const float* G_part = ws + WS_GP;
    const int t = threadIdx.x;

    if (t == 0) lsum = 0.f;
    if (t < NPAIR) {
        float g = 0.f;
        #pragma unroll
        for (int b = 0; b < 16; ++b) g += G_part[b * NPAIR + t];
        G[t] = g;
    }
    __syncthreads();
    if (t < NEXP) {
        int idx = t * NEXP - (t * (t - 1)) / 2;   // diagonal (t,t)
        nr[t] = fmaxf(sqrtf(G[idx]), 1e-8f);
    }
    __syncthreads();
    if (t < NPAIR) {
        int pe = 0, rem = t;
        while (rem >= NEXP - pe) { rem -= NEXP - pe; ++pe; }
        int pf = pe + rem;
        if (pe != pf) {
            float sim = G[t] / (nr[pe] * nr[pf]);
            sim = fminf(1.f, fmaxf(-1.f, sim));
            atomicAdd(&lsum, 2.f * sim);
        }
    }
    __syncthreads();
    if (t == 0) *div_out = lsum / (float)(NEXP * (NEXP - 1)) * 0.1f;
}

extern "C" void kernel_launch(void* const* d_in, const int* in_sizes, int n_in,
                              void* d_out, int out_size, void* d_ws, size_t ws_size,
                              hipStream_t stream) {
    const float* x  = (const float*)d_in[0];
    const float* gw = (const float*)d_in[1];
    const float* gb = (const float*)d_in[2];
    const float* sh = (const float*)d_in[3];
    const float* re = (const float*)d_in[4];
    float* out = (float*)d_out;
    float* ws = (float*)d_ws;   // needs (16384 + 16*1024 + 16*136)*4 ~= 140 KB

    moe_prep<<<16, 256, 0, stream>>>(gw, ws);
    moe_fused<<<2048, 256, 0, stream>>>(x, gb, sh, re, out, ws);
    moe_div_partial<<<16, 320, 0, stream>>>(re, ws);
    moe_div_final<<<1, 192, 0, stream>>>(ws, out + (size_t)NTOK * DDIM);
}